// Round 6
// baseline (962.621 us; speedup 1.0000x reference)
//
#include <hip/hip_runtime.h>
#include <cstddef>
#include <cstdint>

// Problem constants (from reference setup_inputs): B=8, K=64, H=W=384
#define HW 147456
#define BATCH 8
#define KROW 64
#define NBLK_PER_B 128
#define CHUNK 1152   // HW / NBLK_PER_B
#define PSUB 32      // pixels per LDS tile
#define NT 36        // CHUNK / PSUB

// Workspace layout (float offsets). Total ~4.29M floats ~= 17.2 MB.
#define PART_CROSS 0
#define PART_S     (1024 * 4096)            // 4194304
#define CROSS_RED  (PART_S + 1024 * 64)     // 4259840
#define S_RED      (CROSS_RED + 8 * 4096)   // 4292608
#define BTOT       (S_RED + 8 * 64)         // 4293120

// ---------------------------------------------------------------------------
// K1: per (batch, pixel-chunk) block: partial cross[64][64] and partial S[64]
// Each wave computes the FULL 64x64 over its own 8 pixels of each 32-px tile
// (8x8 register tile per thread = 1.0 LDS-bytes/MAC, half of R2's 2.0).
// NO min-waves arg in launch_bounds: R1 proved (256,4) caps VGPR=64 -> spill.
// ---------------------------------------------------------------------------
__global__ __launch_bounds__(256)
void k1_cross(const float* __restrict__ preds, const float* __restrict__ targets,
              float* __restrict__ ws) {
    // smem: X tiles [0,4096) = 2 bufs x 32 px x 64 rows ; T tiles [4096,8192)
    __shared__ float smem[8192];
    const int t   = threadIdx.x;
    const int bid = blockIdx.x;
    const int b   = bid >> 7;
    const int c   = bid & (NBLK_PER_B - 1);
    const int px0 = c * CHUNK;

    const int w  = t >> 6;            // wave 0..3 -> owns pixels [8w, 8w+8)
    const int l  = t & 63;
    const int ti = (l >> 3) * 8;      // row base 0,8,..56
    const int tj = (l & 7) * 8;       // col base 0,8,..56

    // staging mapping: threads <128 stage X (and softplus), >=128 stage T
    const bool matX = (t < 128);
    const int  sthr = t & 127;
    const int  r    = sthr >> 1;   // row 0..63
    const int  half = sthr & 1;    // which 16-px half
    const float* srcRow = (matX ? preds : targets)
        + (size_t)(b * KROW + r) * HW + px0 + 16 * half;
    const int ldsBase = matX ? 0 : 4096;

    float acc[8][8];
#pragma unroll
    for (int a = 0; a < 8; ++a)
#pragma unroll
        for (int q = 0; q < 8; ++q) acc[a][q] = 0.f;

    float sAcc = 0.f;
    float4 ld[4];

    // stage tile 0 into buf 0
    {
        const float4* g = (const float4*)srcRow;
#pragma unroll
        for (int i = 0; i < 4; ++i) ld[i] = g[i];
#pragma unroll
        for (int i = 0; i < 4; ++i) {
            float v[4] = {ld[i].x, ld[i].y, ld[i].z, ld[i].w};
#pragma unroll
            for (int k = 0; k < 4; ++k) {
                if (matX) {
                    const float x = v[k];
                    sAcc += fmaxf(x, 0.f) + log1pf(expf(-fabsf(x)));
                }
                smem[ldsBase + (16 * half + 4 * i + k) * 64 + r] = v[k];
            }
        }
    }
    __syncthreads();

    for (int tile = 0; tile < NT; ++tile) {
        const int  buf  = tile & 1;
        const bool more = (tile + 1 < NT);
        if (more) {  // issue next tile's global loads before compute (latency hide)
            const float4* g = (const float4*)(srcRow + (tile + 1) * PSUB);
#pragma unroll
            for (int i = 0; i < 4; ++i) ld[i] = g[i];
        }
        // compute: full 64x64, this wave's 8 pixels of the tile
        {
            const float* xs = &smem[buf * 2048 + (w * 8) * 64 + ti];
            const float* ts = &smem[4096 + buf * 2048 + (w * 8) * 64 + tj];
#pragma unroll 2
            for (int p = 0; p < 8; ++p) {
                const float4 xv0 = *(const float4*)(xs + p * 64);
                const float4 xv1 = *(const float4*)(xs + p * 64 + 4);
                const float4 tv0 = *(const float4*)(ts + p * 64);
                const float4 tv1 = *(const float4*)(ts + p * 64 + 4);
                const float xa[8] = {xv0.x, xv0.y, xv0.z, xv0.w,
                                     xv1.x, xv1.y, xv1.z, xv1.w};
                const float ta[8] = {tv0.x, tv0.y, tv0.z, tv0.w,
                                     tv1.x, tv1.y, tv1.z, tv1.w};
#pragma unroll
                for (int a = 0; a < 8; ++a)
#pragma unroll
                    for (int q = 0; q < 8; ++q)
                        acc[a][q] += xa[a] * ta[q];
            }
        }
        if (more) {
            __syncthreads();   // everyone done reading current buf
            const int nbuf = buf ^ 1;
#pragma unroll
            for (int i = 0; i < 4; ++i) {
                float v[4] = {ld[i].x, ld[i].y, ld[i].z, ld[i].w};
#pragma unroll
                for (int k = 0; k < 4; ++k) {
                    if (matX) {
                        const float x = v[k];
                        sAcc += fmaxf(x, 0.f) + log1pf(expf(-fabsf(x)));
                    }
                    smem[ldsBase + nbuf * 2048 + (16 * half + 4 * i + k) * 64 + r] = v[k];
                }
            }
            __syncthreads();
        }
    }

    // cross-wave reduction of acc into smem[0,4096) (one-time, 4 passes)
    __syncthreads();
    for (int ww = 0; ww < 4; ++ww) {
        if (w == ww) {
#pragma unroll
            for (int a = 0; a < 8; ++a)
#pragma unroll
                for (int q = 0; q < 8; ++q) {
                    const int idx = (ti + a) * 64 + tj + q;
                    if (ww == 0) smem[idx] = acc[a][q];
                    else         smem[idx] += acc[a][q];
                }
        }
        __syncthreads();
    }
    // write partial cross (coalesced float4)
    {
        float4* dst = (float4*)(ws + (size_t)PART_CROSS + (size_t)bid * 4096);
        const float4* s4 = (const float4*)smem;
#pragma unroll
        for (int k = 0; k < 4; ++k) dst[t + 256 * k] = s4[t + 256 * k];
    }
    // partial S: pair-reduce the two threads sharing a row
    {
        const float s2 = sAcc + __shfl_xor(sAcc, 1);
        if (matX && ((t & 1) == 0))
            ws[PART_S + (size_t)bid * 64 + r] = s2;
    }
}

// ---------------------------------------------------------------------------
// K2: reduce 128 partials per batch -> cross_red[8][4096], S_red[8][64]
// ---------------------------------------------------------------------------
__global__ __launch_bounds__(256)
void k2_reduce(float* __restrict__ ws) {
    const int t = threadIdx.x;
    const int g = blockIdx.x;   // 0..16
    const int b = blockIdx.y;   // 0..7
    if (g < 16) {
        const int e = g * 256 + t;
        const float* p = ws + (size_t)PART_CROSS + (size_t)b * NBLK_PER_B * 4096 + e;
        float s = 0.f;
#pragma unroll 8
        for (int c = 0; c < NBLK_PER_B; ++c) s += p[(size_t)c * 4096];
        ws[CROSS_RED + (size_t)b * 4096 + e] = s;
    } else if (t < 64) {
        const float* p = ws + (size_t)PART_S + (size_t)b * NBLK_PER_B * 64 + t;
        float s = 0.f;
#pragma unroll 8
        for (int c = 0; c < NBLK_PER_B; ++c) s += p[c * 64];
        ws[S_RED + b * 64 + t] = s;
    }
}

// ---------------------------------------------------------------------------
// K3: per-batch sinkhorn (exact reference replica) + <P, C>
// ---------------------------------------------------------------------------
__global__ __launch_bounds__(256)
void k3_sinkhorn(float* __restrict__ ws) {
    __shared__ float Q[64 * 65];
    __shared__ float wred[4];
    const int t  = threadIdx.x;
    const int b  = blockIdx.x;
    const int i  = t >> 2;
    const int qq = t & 3;
    const float* cr = ws + CROSS_RED + (size_t)b * 4096;
    const float S_i = ws[S_RED + b * 64 + i];

    // Q0 = -cost = cross - S_i ; row max
    float q0[16];
    float m = -3.4e38f;
#pragma unroll
    for (int n = 0; n < 16; ++n) {
        const float v = cr[i * 64 + qq * 16 + n] - S_i;
        q0[n] = v;
        m = fmaxf(m, v);
    }
    m = fmaxf(m, __shfl_xor(m, 1));
    m = fmaxf(m, __shfl_xor(m, 2));
    // exp(clip((q-m)/REG, -10, 10)) ; row normalize with +EPS
    float rs = 0.f;
#pragma unroll
    for (int n = 0; n < 16; ++n) {
        const float e = expf(fminf(fmaxf((q0[n] - m) / 0.1f, -10.f), 10.f));
        q0[n] = e;
        rs += e;
    }
    rs += __shfl_xor(rs, 1);
    rs += __shfl_xor(rs, 2);
    const float inv = 1.f / (rs + 1e-8f);
#pragma unroll
    for (int n = 0; n < 16; ++n) Q[i * 65 + qq * 16 + n] = q0[n] * inv;
    __syncthreads();

    const int jc  = t >> 2;
    const int i16 = (t & 3) * 16;
    for (int it = 0; it < 20; ++it) {
        // row rescale: Q *= r / (rowsum + EPS), r = 1/64
        float u = 0.f;
#pragma unroll
        for (int n = 0; n < 16; ++n) u += Q[i * 65 + qq * 16 + n];
        u += __shfl_xor(u, 1);
        u += __shfl_xor(u, 2);
        const float f = 0.015625f / (u + 1e-8f);
#pragma unroll
        for (int n = 0; n < 16; ++n) Q[i * 65 + qq * 16 + n] *= f;
        __syncthreads();
        // col rescale: Q *= c / (colsum + EPS), c = 1/64
        float vv = 0.f;
#pragma unroll
        for (int n = 0; n < 16; ++n) vv += Q[(i16 + n) * 65 + jc];
        vv += __shfl_xor(vv, 1);
        vv += __shfl_xor(vv, 2);
        const float g2 = 0.015625f / (vv + 1e-8f);
#pragma unroll
        for (int n = 0; n < 16; ++n) Q[(i16 + n) * 65 + jc] *= g2;
        __syncthreads();
    }

    // total_b = sum(P * cost), cost = S_i - cross
    float tot = 0.f;
#pragma unroll
    for (int n = 0; n < 16; ++n) {
        const int j = qq * 16 + n;
        const float cost = S_i - cr[i * 64 + j];
        tot += Q[i * 65 + j] * cost;
    }
#pragma unroll
    for (int s = 1; s < 64; s <<= 1) tot += __shfl_xor(tot, s);
    if ((t & 63) == 0) wred[t >> 6] = tot;
    __syncthreads();
    if (t == 0) ws[BTOT + b] = wred[0] + wred[1] + wred[2] + wred[3];
}

// ---------------------------------------------------------------------------
// K4: final scalar
// ---------------------------------------------------------------------------
__global__ void k4_final(const float* __restrict__ ws, float* __restrict__ out) {
    const int t = threadIdx.x;
    float v = (t < 8) ? ws[BTOT + t] : 0.f;
    v += __shfl_xor(v, 1);
    v += __shfl_xor(v, 2);
    v += __shfl_xor(v, 4);
    if (t == 0) out[0] = v / (float)HW;
}

extern "C" void kernel_launch(void* const* d_in, const int* in_sizes, int n_in,
                              void* d_out, int out_size, void* d_ws, size_t ws_size,
                              hipStream_t stream) {
    const float* preds   = (const float*)d_in[0];
    const float* targets = (const float*)d_in[1];
    float* ws  = (float*)d_ws;
    float* out = (float*)d_out;

    hipLaunchKernelGGL(k1_cross,    dim3(1024),   dim3(256), 0, stream, preds, targets, ws);
    hipLaunchKernelGGL(k2_reduce,   dim3(17, 8),  dim3(256), 0, stream, ws);
    hipLaunchKernelGGL(k3_sinkhorn, dim3(8),      dim3(256), 0, stream, ws);
    hipLaunchKernelGGL(k4_final,    dim3(1),      dim3(64),  0, stream, ws, out);
}

// Round 10
// 699.872 us; speedup vs baseline: 1.3754x; 1.3754x over previous
//
#include <hip/hip_runtime.h>
#include <cstddef>
#include <cstdint>

// Problem constants: B=8, K=64, H=W=384
#define HW 147456
#define NBLK_PER_B 128
#define CHUNK 1152   // HW / NBLK_PER_B
#define PSUB 32      // pixels (K-dim) per LDS chunk = one mfma K=32 step
#define NT 36        // CHUNK / PSUB

// Workspace layout (float offsets). ~17.2 MB.
#define PART_CROSS 0
#define PART_S     (1024 * 4096)
#define CROSS_RED  (PART_S + 1024 * 64)
#define S_RED      (CROSS_RED + 8 * 4096)
#define BTOT       (S_RED + 8 * 64)

typedef __attribute__((ext_vector_type(8))) short bf16x8;  // 4 VGPRs, MFMA A/B frag
typedef __attribute__((ext_vector_type(4))) float f32x4;   // MFMA C/D frag

__device__ __forceinline__ unsigned short f2bf(float x) {   // fp32 -> bf16 RNE
    unsigned int u = __float_as_uint(x);
    u = (u + 0x7FFFu + ((u >> 16) & 1u)) >> 16;
    return (unsigned short)u;
}
__device__ __forceinline__ float bf2f(unsigned short h) {
    return __uint_as_float(((unsigned int)h) << 16);
}

// LDS plane: [64 rows][32 px + 8 pad] bf16 -> 2560 shorts (row stride 80 B)
#define ROWS 40
#define PLANE 2560

// convert 8 X floats + 8 T floats to bf16 hi/lo planes, return softplus partial
__device__ __forceinline__ float stage_convert(
    const float4& a0, const float4& a1, const float4& b0, const float4& b1,
    short* dXh, short* dXl, short* dTh, short* dTl)
{
    const float xv[8] = {a0.x, a0.y, a0.z, a0.w, a1.x, a1.y, a1.z, a1.w};
    const float tv[8] = {b0.x, b0.y, b0.z, b0.w, b1.x, b1.y, b1.z, b1.w};
    bf16x8 xh, xl, th, tl;
    float sp = 0.f;
#pragma unroll
    for (int j = 0; j < 8; ++j) {
        const float x = xv[j];
        sp += fmaxf(x, 0.f) + log1pf(expf(-fabsf(x)));
        const unsigned short h = f2bf(x);
        xh[j] = (short)h;
        xl[j] = (short)f2bf(x - bf2f(h));
        const float y = tv[j];
        const unsigned short g = f2bf(y);
        th[j] = (short)g;
        tl[j] = (short)f2bf(y - bf2f(g));
    }
    *(bf16x8*)dXh = xh;
    *(bf16x8*)dXl = xl;
    *(bf16x8*)dTh = th;
    *(bf16x8*)dTl = tl;
    return sp;
}

// ---------------------------------------------------------------------------
// K1 (MFMA): per (batch, chunk) block -> partial cross[64][64], partial S[64].
// bf16-split (hi+lo) of both inputs; cross = Xh*Th + Xh*Tl + Xl*Th via
// mfma_f32_16x16x32_bf16 (layouts HW-verified: A lane row=l&15,k=(l>>4)*8+j;
// C/D col=l&15,row=(l>>4)*4+reg). Wave w owns 32x32 quadrant -> no x-wave
// reduction. R6 lesson: vector-FMA path is VALU-issue-bound at 5x FMA floor.
// ---------------------------------------------------------------------------
__global__ __launch_bounds__(256)
void k1_cross(const float* __restrict__ preds, const float* __restrict__ targets,
              float* __restrict__ ws) {
    __shared__ short smem[2 * 4 * PLANE];  // [buf][Xhi,Xlo,Thi,Tlo][64][40]
    const int t   = threadIdx.x;
    const int bid = blockIdx.x;
    const int b   = bid >> 7;
    const int c   = bid & 127;
    const int px0 = c * CHUNK;

    const int w   = t >> 6, l = t & 63;
    const int wr  = (w >> 1) * 32;   // quadrant row base
    const int wc  = (w & 1) * 32;    // quadrant col base
    const int r16 = l & 15;          // fragment row/col within 16-tile
    const int kg  = l >> 4;          // k-group 0..3 (8 px each)

    // staging: thread t owns 8 px of row r (both X and T)
    const int r = t >> 2, q = t & 3;
    const float* srcX = preds   + (size_t)(b * 64 + r) * HW + px0 + 8 * q;
    const float* srcT = targets + (size_t)(b * 64 + r) * HW + px0 + 8 * q;
    const int wsh = r * ROWS + 8 * q;   // short offset within a plane

    f32x4 acc[2][2];
#pragma unroll
    for (int mi = 0; mi < 2; ++mi)
#pragma unroll
        for (int nj = 0; nj < 2; ++nj)
#pragma unroll
            for (int e = 0; e < 4; ++e) acc[mi][nj][e] = 0.f;

    float sAcc = 0.f;
    float4 lx0, lx1, lt0, lt1;

    // prologue: chunk 0 -> buf 0
    lx0 = *(const float4*)(srcX);
    lx1 = *(const float4*)(srcX + 4);
    lt0 = *(const float4*)(srcT);
    lt1 = *(const float4*)(srcT + 4);
    sAcc += stage_convert(lx0, lx1, lt0, lt1,
                          smem + 0 * PLANE + wsh, smem + 1 * PLANE + wsh,
                          smem + 2 * PLANE + wsh, smem + 3 * PLANE + wsh);
    __syncthreads();

    for (int chunk = 0; chunk < NT; ++chunk) {
        const int  buf  = chunk & 1;
        const bool more = (chunk + 1 < NT);
        if (more) {  // prefetch next chunk into regs (hides under MFMA phase)
            const float* pX = srcX + (chunk + 1) * PSUB;
            const float* pT = srcT + (chunk + 1) * PSUB;
            lx0 = *(const float4*)(pX);
            lx1 = *(const float4*)(pX + 4);
            lt0 = *(const float4*)(pT);
            lt1 = *(const float4*)(pT + 4);
        }
        // fragment loads + 12 MFMA (2x2 tiles x 3 split-terms)
        {
            const short* sb = smem + buf * 4 * PLANE;
            bf16x8 ah[2], al[2], bh[2], bl[2];
#pragma unroll
            for (int mi = 0; mi < 2; ++mi) {
                const int offA = (wr + mi * 16 + r16) * ROWS + kg * 8;
                ah[mi] = *(const bf16x8*)(sb + 0 * PLANE + offA);
                al[mi] = *(const bf16x8*)(sb + 1 * PLANE + offA);
                const int offB = (wc + mi * 16 + r16) * ROWS + kg * 8;
                bh[mi] = *(const bf16x8*)(sb + 2 * PLANE + offB);
                bl[mi] = *(const bf16x8*)(sb + 3 * PLANE + offB);
            }
#pragma unroll
            for (int mi = 0; mi < 2; ++mi)
#pragma unroll
                for (int nj = 0; nj < 2; ++nj) {
                    acc[mi][nj] = __builtin_amdgcn_mfma_f32_16x16x32_bf16(
                        ah[mi], bh[nj], acc[mi][nj], 0, 0, 0);
                    acc[mi][nj] = __builtin_amdgcn_mfma_f32_16x16x32_bf16(
                        ah[mi], bl[nj], acc[mi][nj], 0, 0, 0);
                    acc[mi][nj] = __builtin_amdgcn_mfma_f32_16x16x32_bf16(
                        al[mi], bh[nj], acc[mi][nj], 0, 0, 0);
                }
        }
        if (more) {
            __syncthreads();   // all waves done reading buf (and buf^1 2 bars ago)
            const int nb = (buf ^ 1) * 4 * PLANE;
            sAcc += stage_convert(lx0, lx1, lt0, lt1,
                                  smem + nb + 0 * PLANE + wsh,
                                  smem + nb + 1 * PLANE + wsh,
                                  smem + nb + 2 * PLANE + wsh,
                                  smem + nb + 3 * PLANE + wsh);
            __syncthreads();
        }
    }

    // epilogue: write partial cross. C/D: col=l&15, row=(l>>4)*4+reg
    {
        float* dst = ws + (size_t)PART_CROSS + (size_t)bid * 4096;
#pragma unroll
        for (int mi = 0; mi < 2; ++mi)
#pragma unroll
            for (int nj = 0; nj < 2; ++nj)
#pragma unroll
                for (int e = 0; e < 4; ++e) {
                    const int row = wr + mi * 16 + kg * 4 + e;
                    const int col = wc + nj * 16 + r16;
                    dst[row * 64 + col] = acc[mi][nj][e];
                }
    }
    // partial S: reduce the 4 threads sharing row r (consecutive lanes)
    {
        float s2 = sAcc + __shfl_xor(sAcc, 1);
        s2 += __shfl_xor(s2, 2);
        if (q == 0) ws[PART_S + (size_t)bid * 64 + r] = s2;
    }
}

// ---------------------------------------------------------------------------
// K2: reduce 128 partials per batch -> cross_red[8][4096], S_red[8][64]
// ---------------------------------------------------------------------------
__global__ __launch_bounds__(256)
void k2_reduce(float* __restrict__ ws) {
    const int t = threadIdx.x;
    const int g = blockIdx.x;   // 0..16
    const int b = blockIdx.y;   // 0..7
    if (g < 16) {
        const int e = g * 256 + t;
        const float* p = ws + (size_t)PART_CROSS + (size_t)b * NBLK_PER_B * 4096 + e;
        float s = 0.f;
#pragma unroll 8
        for (int c = 0; c < NBLK_PER_B; ++c) s += p[(size_t)c * 4096];
        ws[CROSS_RED + (size_t)b * 4096 + e] = s;
    } else if (t < 64) {
        const float* p = ws + (size_t)PART_S + (size_t)b * NBLK_PER_B * 64 + t;
        float s = 0.f;
#pragma unroll 8
        for (int c = 0; c < NBLK_PER_B; ++c) s += p[c * 64];
        ws[S_RED + b * 64 + t] = s;
    }
}

// ---------------------------------------------------------------------------
// K3: per-batch sinkhorn (exact reference replica) + <P, C>
// ---------------------------------------------------------------------------
__global__ __launch_bounds__(256)
void k3_sinkhorn(float* __restrict__ ws) {
    __shared__ float Q[64 * 65];
    __shared__ float wred[4];
    const int t  = threadIdx.x;
    const int b  = blockIdx.x;
    const int i  = t >> 2;
    const int qq = t & 3;
    const float* cr = ws + CROSS_RED + (size_t)b * 4096;
    const float S_i = ws[S_RED + b * 64 + i];

    float q0[16];
    float m = -3.4e38f;
#pragma unroll
    for (int n = 0; n < 16; ++n) {
        const float v = cr[i * 64 + qq * 16 + n] - S_i;
        q0[n] = v;
        m = fmaxf(m, v);
    }
    m = fmaxf(m, __shfl_xor(m, 1));
    m = fmaxf(m, __shfl_xor(m, 2));
    float rs = 0.f;
#pragma unroll
    for (int n = 0; n < 16; ++n) {
        const float e = expf(fminf(fmaxf((q0[n] - m) / 0.1f, -10.f), 10.f));
        q0[n] = e;
        rs += e;
    }
    rs += __shfl_xor(rs, 1);
    rs += __shfl_xor(rs, 2);
    const float inv = 1.f / (rs + 1e-8f);
#pragma unroll
    for (int n = 0; n < 16; ++n) Q[i * 65 + qq * 16 + n] = q0[n] * inv;
    __syncthreads();

    const int jc  = t >> 2;
    const int i16 = (t & 3) * 16;
    for (int it = 0; it < 20; ++it) {
        float u = 0.f;
#pragma unroll
        for (int n = 0; n < 16; ++n) u += Q[i * 65 + qq * 16 + n];
        u += __shfl_xor(u, 1);
        u += __shfl_xor(u, 2);
        const float f = 0.015625f / (u + 1e-8f);
#pragma unroll
        for (int n = 0; n < 16; ++n) Q[i * 65 + qq * 16 + n] *= f;
        __syncthreads();
        float vv = 0.f;
#pragma unroll
        for (int n = 0; n < 16; ++n) vv += Q[(i16 + n) * 65 + jc];
        vv += __shfl_xor(vv, 1);
        vv += __shfl_xor(vv, 2);
        const float g2 = 0.015625f / (vv + 1e-8f);
#pragma unroll
        for (int n = 0; n < 16; ++n) Q[(i16 + n) * 65 + jc] *= g2;
        __syncthreads();
    }

    float tot = 0.f;
#pragma unroll
    for (int n = 0; n < 16; ++n) {
        const int j = qq * 16 + n;
        const float cost = S_i - cr[i * 64 + j];
        tot += Q[i * 65 + j] * cost;
    }
#pragma unroll
    for (int s = 1; s < 64; s <<= 1) tot += __shfl_xor(tot, s);
    if ((t & 63) == 0) wred[t >> 6] = tot;
    __syncthreads();
    if (t == 0) ws[BTOT + b] = wred[0] + wred[1] + wred[2] + wred[3];
}

// ---------------------------------------------------------------------------
// K4: final scalar
// ---------------------------------------------------------------------------
__global__ void k4_final(const float* __restrict__ ws, float* __restrict__ out) {
    const int t = threadIdx.x;
    float v = (t < 8) ? ws[BTOT + t] : 0.f;
    v += __shfl_xor(v, 1);
    v += __shfl_xor(v, 2);
    v += __shfl_xor(v, 4);
    if (t == 0) out[0] = v / (float)HW;
}

extern "C" void kernel_launch(void* const* d_in, const int* in_sizes, int n_in,
                              void* d_out, int out_size, void* d_ws, size_t ws_size,
                              hipStream_t stream) {
    const float* preds   = (const float*)d_in[0];
    const float* targets = (const float*)d_in[1];
    float* ws  = (float*)d_ws;
    float* out = (float*)d_out;

    hipLaunchKernelGGL(k1_cross,    dim3(1024),  dim3(256), 0, stream, preds, targets, ws);
    hipLaunchKernelGGL(k2_reduce,   dim3(17, 8), dim3(256), 0, stream, ws);
    hipLaunchKernelGGL(k3_sinkhorn, dim3(8),     dim3(256), 0, stream, ws);
    hipLaunchKernelGGL(k4_final,    dim3(1),     dim3(64),  0, stream, ws, out);
}